// Round 7
// baseline (110.145 us; speedup 1.0000x reference)
//
#include <hip/hip_runtime.h>
#include <hip/hip_bf16.h>
#include <math.h>

#define S_LEN 2048
#define DM    1024
#define NH    16
#define DH    64
#define CHUNK 64
#define NCH   (S_LEN / CHUNK)          // 32
#define ST_STRIDE (DH * DH + DH)       // 4160 floats per (head,chunk) state

typedef __attribute__((ext_vector_type(8))) short bf16x8;   // 8 bf16 in 4 VGPRs
typedef __attribute__((ext_vector_type(4))) float f32x4;

__device__ __forceinline__ float softplus_f(float x) {
    return (x > 20.0f) ? x : log1pf(expf(x));
}

__device__ __forceinline__ ushort bf16r(float f) {   // round-to-nearest-even f32 -> bf16
    union { float f; unsigned int u; } c; c.f = f;
    unsigned int u = c.u;
    u = (u + 0x7FFFu + ((u >> 16) & 1u)) >> 16;
    return (ushort)u;
}

// ---------------- casts ----------------
__global__ __launch_bounds__(256) void cast_x_kernel(const float* __restrict__ src,
                                                     ushort* __restrict__ dst) {
    const int i = (blockIdx.x * 256 + threadIdx.x) * 4;
    const float4 v = *(const float4*)(src + i);
    ushort4 o; o.x = bf16r(v.x); o.y = bf16r(v.y); o.z = bf16r(v.z); o.w = bf16r(v.w);
    *(ushort4*)(dst + i) = o;
}

__global__ __launch_bounds__(256) void cast_w_kernel(const float* __restrict__ Wq,
                                                     const float* __restrict__ Wk,
                                                     const float* __restrict__ Wv,
                                                     const float* __restrict__ Wo,
                                                     ushort* __restrict__ dst) {
    const int y = blockIdx.y;
    const float* s = (y == 0) ? Wq : (y == 1) ? Wk : (y == 2) ? Wv : Wo;
    const int i = (blockIdx.x * 256 + threadIdx.x) * 4;
    const float4 v = *(const float4*)(s + i);
    ushort4 o; o.x = bf16r(v.x); o.y = bf16r(v.y); o.z = bf16r(v.z); o.w = bf16r(v.w);
    *(ushort4*)(dst + (size_t)y * (DM * DM) + i) = o;
}

// ============ QKV GEMM: m201-class schedule, BM=128 x BN=256, K_STEP=64, depth-3 ============
// A = Xb [2048][1024] bf16 rm, B = Wqkv [3072][1024] bf16 rm (row = out feature).
// 192 blocks (16 m x 12 n), 8 waves (2x4), wave tile 64x64 (4x4 16x16x32 frags).
// LDS: 3 buffers x (A 16KB + B 32KB) = 144 KB.  Chunks = 8 rows x 64 elems = 1KB, staged by
// one wave-gload_lds (lane l -> row l>>3, granule l&7).  Swizzle: granule_phys = granule ^
// (row&7) via inverse-swizzled GLOBAL source (linear LDS dest, rule 21); reads apply same XOR.
// Sync per K-tile: counted s_waitcnt vmcnt(6) (t's 6 loads done, t+1's 6 stay in flight) ->
// one s_barrier -> 2 phases {8 ds_read | stage half of t+2 | setprio(1) 16 MFMA setprio(0)}.
// Buffer (t+2)%3 overwritten = buffer retired at the barrier 3 tiles ago -> race-free.
__global__ __launch_bounds__(512)
void qkv_gemm_kernel(const ushort* __restrict__ Xb, const ushort* __restrict__ Wqkv,
                     const float* __restrict__ bq, const float* __restrict__ bk,
                     const float* __restrict__ bv,
                     const float* __restrict__ beta,
                     float* __restrict__ qkv /* q|k|v contiguous */)
{
    constexpr int NT  = 16;          // K tiles of 64
    constexpr int ASZ = 128 * 64;    // ushorts per A buffer
    constexpr int BSZ = 256 * 64;    // ushorts per B buffer
    __shared__ ushort Als[3 * ASZ];  // 48 KB
    __shared__ ushort Bls[3 * BSZ];  // 96 KB

    const int b = blockIdx.x;
    const int logical = (b & 7) * 24 + (b >> 3);      // XCD x owns 24 consecutive logicals
    const int mb = logical & 15, nb = logical >> 4;   // m-fastest: A panel L2-resident per XCD
    const int m0 = mb * 128, n0 = nb * 256;
    const int z  = nb >> 2;                           // 0:q 1:k 2:v
    const int nz0 = (nb & 3) * 256;                   // col base within this z
    const float* bias = (z == 0) ? bq : (z == 1) ? bk : bv;

    const int t = threadIdx.x, w = t >> 6, l = t & 63;
    const int wr = w >> 2, wc = w & 3;                // 2x4 wave grid
    const int r8 = l >> 3, gl = l & 7;
    const int scol = ((gl ^ r8) << 3);                // inverse-swizzled source col (elems)
    const int frow = l & 15, kq = l >> 4;
    const int fswz0 = ((kq ^ (frow & 7)) << 3);       // k-sub 0 read granule (elems)
    const int fswz1 = (((4 + kq) ^ (frow & 7)) << 3); // k-sub 1

    f32x4 acc[4][4];
#pragma unroll
    for (int mi = 0; mi < 4; ++mi)
#pragma unroll
        for (int ni = 0; ni < 4; ++ni) acc[mi][ni] = (f32x4){0.f, 0.f, 0.f, 0.f};

    auto STAGE_A = [&](int buf, int kt) {             // 2 gloads/wave
#pragma unroll
        for (int ci = 0; ci < 2; ++ci) {
            const int c = w + ci * 8;                 // chunk 0..15
            __builtin_amdgcn_global_load_lds(
                (const __attribute__((address_space(1))) void*)(Xb + (size_t)(m0 + c * 8 + r8) * DM + kt + scol),
                (__attribute__((address_space(3))) void*)(Als + buf * ASZ + c * 512), 16, 0, 0);
        }
    };
    auto STAGE_B = [&](int buf, int kt) {             // 4 gloads/wave
#pragma unroll
        for (int ci = 0; ci < 4; ++ci) {
            const int c = w + ci * 8;                 // chunk 0..31
            __builtin_amdgcn_global_load_lds(
                (const __attribute__((address_space(1))) void*)(Wqkv + (size_t)(n0 + c * 8 + r8) * DM + kt + scol),
                (__attribute__((address_space(3))) void*)(Bls + buf * BSZ + c * 512), 16, 0, 0);
        }
    };

    STAGE_A(0, 0);  STAGE_B(0, 0);
    STAGE_A(1, 64); STAGE_B(1, 64);

    int cur = 0, nxt = 2;
    for (int tt = 0; tt < NT; ++tt) {
        // counted wait: own tile-t loads landed; tile-(t+1) loads stay in flight
        if (tt + 1 < NT) asm volatile("s_waitcnt vmcnt(6)" ::: "memory");
        else             asm volatile("s_waitcnt vmcnt(0)" ::: "memory");
        __builtin_amdgcn_s_barrier();           // all waves' tile-t loads landed; tile-(t-1) reads retired
        asm volatile("" ::: "memory");

        const ushort* Ab_ = Als + cur * ASZ;
        const ushort* Bb_ = Bls + cur * BSZ;
        const int kt2 = (tt + 2) * 64;
        const bool do2 = (tt + 2 < NT);

        // ---- phase 0: k-sub 0 ----
        bf16x8 af0[4], bf0[4];
#pragma unroll
        for (int mi = 0; mi < 4; ++mi)
            af0[mi] = *(const bf16x8*)&Ab_[(wr * 64 + mi * 16 + frow) * 64 + fswz0];
#pragma unroll
        for (int ni = 0; ni < 4; ++ni)
            bf0[ni] = *(const bf16x8*)&Bb_[(wc * 64 + ni * 16 + frow) * 64 + fswz0];
        if (do2) STAGE_A(nxt, kt2);             // issue-early: hides under MFMA below
        __builtin_amdgcn_s_setprio(1);
#pragma unroll
        for (int mi = 0; mi < 4; ++mi)
#pragma unroll
            for (int ni = 0; ni < 4; ++ni)
                acc[mi][ni] = __builtin_amdgcn_mfma_f32_16x16x32_bf16(af0[mi], bf0[ni], acc[mi][ni], 0, 0, 0);
        __builtin_amdgcn_s_setprio(0);

        // ---- phase 1: k-sub 1 ----
        bf16x8 af1[4], bf1[4];
#pragma unroll
        for (int mi = 0; mi < 4; ++mi)
            af1[mi] = *(const bf16x8*)&Ab_[(wr * 64 + mi * 16 + frow) * 64 + fswz1];
#pragma unroll
        for (int ni = 0; ni < 4; ++ni)
            bf1[ni] = *(const bf16x8*)&Bb_[(wc * 64 + ni * 16 + frow) * 64 + fswz1];
        if (do2) STAGE_B(nxt, kt2);
        __builtin_amdgcn_s_setprio(1);
#pragma unroll
        for (int mi = 0; mi < 4; ++mi)
#pragma unroll
            for (int ni = 0; ni < 4; ++ni)
                acc[mi][ni] = __builtin_amdgcn_mfma_f32_16x16x32_bf16(af1[mi], bf1[ni], acc[mi][ni], 0, 0, 0);
        __builtin_amdgcn_s_setprio(0);

        asm volatile("" ::: "memory");
        cur = (cur == 2) ? 0 : cur + 1;
        nxt = (nxt == 2) ? 0 : nxt + 1;
    }

    // epilogue: bias + softplus (q,k), head-layout scatter
    const int colb = nz0 + wc * 64;               // one head per wave-column
    const int h = colb >> 6;
    const float inv = (z < 2) ? (1.0f / (8.0f * expf(beta[h]))) : 1.0f;
    float* outz = qkv + (size_t)z * (NH * S_LEN * DH);
#pragma unroll
    for (int ni = 0; ni < 4; ++ni) {
        const int d0 = ni * 16 + (l & 15);
        const float bcol = bias[colb + d0];
#pragma unroll
        for (int mi = 0; mi < 4; ++mi) {
            const int rbase = m0 + wr * 64 + mi * 16 + (l >> 4) * 4;
#pragma unroll
            for (int r = 0; r < 4; ++r) {
                float v = acc[mi][ni][r] + bcol;
                if (z < 2) v = softplus_f(v * inv);
                outz[((size_t)h * S_LEN + rbase + r) * DH + d0] = v;
            }
        }
    }
}

// ---------------- legacy core (o_gemm): depth-2 counted-vmcnt, granule swizzle ----------------
template<int BN, int WR, int WC>
__device__ __forceinline__ void gemm_core(const ushort* __restrict__ A,
                                          const ushort* __restrict__ Bw,
                                          int m0, int n0,
                                          ushort* Als, ushort* Bls,
                                          f32x4 acc[128 / (WR * 16)][BN / (WC * 16)])
{
    constexpr int MF  = 128 / (WR * 16);
    constexpr int NF  = BN / (WC * 16);
    constexpr int NW  = WR * WC;
    constexpr int ASZ = 128 * 32;
    constexpr int BSZ = BN * 32;
    constexpr int LPW = (8 + BN / 16) / NW;
    constexpr int NT  = DM / 32;

    const int t = threadIdx.x;
    const int w = t >> 6, l = t & 63;
    const int wr = w / WC, wc = w % WC;

#pragma unroll
    for (int mi = 0; mi < MF; ++mi)
#pragma unroll
        for (int ni = 0; ni < NF; ++ni) acc[mi][ni] = (f32x4){0.f, 0.f, 0.f, 0.f};

    const int srow = l >> 2;
    const int scol = ((l & 3) ^ ((l >> 3) & 3)) * 8;
    const int frow = l & 15;
    const int gofs = ((l >> 4) ^ ((l >> 1) & 3)) * 8;

    auto STAGE = [&](int buf, int kt) {
        ushort* Ad = Als + buf * ASZ;
        ushort* Bd = Bls + buf * BSZ;
        __builtin_amdgcn_global_load_lds(
            (const __attribute__((address_space(1))) void*)(A + (size_t)(m0 + w * 16 + srow) * DM + kt + scol),
            (__attribute__((address_space(3))) void*)(Ad + w * 512), 16, 0, 0);
        __builtin_amdgcn_global_load_lds(
            (const __attribute__((address_space(1))) void*)(A + (size_t)(m0 + (w + 4) * 16 + srow) * DM + kt + scol),
            (__attribute__((address_space(3))) void*)(Ad + (w + 4) * 512), 16, 0, 0);
        __builtin_amdgcn_global_load_lds(
            (const __attribute__((address_space(1))) void*)(Bw + (size_t)(n0 + w * 16 + srow) * DM + kt + scol),
            (__attribute__((address_space(3))) void*)(Bd + w * 512), 16, 0, 0);
    };

    STAGE(0, 0);
    STAGE(1, 32);

    int cur = 0;
    for (int tt = 0; tt < NT; ++tt) {
        if (tt + 1 < NT) asm volatile("s_waitcnt vmcnt(%0)" :: "i"(LPW) : "memory");
        else             asm volatile("s_waitcnt vmcnt(0)" ::: "memory");
        __builtin_amdgcn_s_barrier();
        asm volatile("" ::: "memory");

        const ushort* Ab_ = Als + cur * ASZ;
        const ushort* Bb_ = Bls + cur * BSZ;
        bf16x8 af[MF], bfr[NF];
#pragma unroll
        for (int mi = 0; mi < MF; ++mi)
            af[mi] = *(const bf16x8*)&Ab_[(wr * (128 / WR) + mi * 16 + frow) * 32 + gofs];
#pragma unroll
        for (int ni = 0; ni < NF; ++ni)
            bfr[ni] = *(const bf16x8*)&Bb_[(wc * (BN / WC) + ni * 16 + frow) * 32 + gofs];
#pragma unroll
        for (int mi = 0; mi < MF; ++mi)
#pragma unroll
            for (int ni = 0; ni < NF; ++ni)
                acc[mi][ni] = __builtin_amdgcn_mfma_f32_16x16x32_bf16(af[mi], bfr[ni], acc[mi][ni], 0, 0, 0);

        asm volatile("" ::: "memory");
        __builtin_amdgcn_s_barrier();
        asm volatile("" ::: "memory");
        if (tt + 2 < NT) STAGE(cur, (tt + 2) * 32);
        cur ^= 1;
    }
}

// O projection: C = out_pre(bf16) @ Wo^T + bo -> fp32 [2048][1024].  256 tiles, XCD-swizzled.
__global__ __launch_bounds__(256)
void o_gemm_kernel(const ushort* __restrict__ Ab, const ushort* __restrict__ Wob,
                   const float* __restrict__ bo, float* __restrict__ out)
{
    __shared__ ushort Als[2 * 128 * 32];
    __shared__ ushort Bls[2 * 64 * 32];
    const int b = blockIdx.x;
    const int logical = (b & 7) * 32 + (b >> 3);
    const int mb = logical & 15, nb = logical >> 4;
    const int m0 = mb * 128;
    const int n0 = nb * 64;

    f32x4 acc[4][2];
    gemm_core<64, 2, 2>(Ab, Wob, m0, n0, Als, Bls, acc);

    const int t = threadIdx.x, w = t >> 6, l = t & 63;
    const int wr = w >> 1, wc = w & 1;
#pragma unroll
    for (int ni = 0; ni < 2; ++ni) {
        const int col = n0 + wc * 32 + ni * 16 + (l & 15);
        const float bcol = bo[col];
#pragma unroll
        for (int mi = 0; mi < 4; ++mi) {
            const int rbase = m0 + wr * 64 + mi * 16 + (l >> 4) * 4;
#pragma unroll
            for (int r = 0; r < 4; ++r)
                out[(size_t)(rbase + r) * DM + col] = acc[mi][ni][r] + bcol;
        }
    }
}

// ---------------- Pass B: per (head, chunk) state ----------------
__global__ __launch_bounds__(256)
void chunk_state_kernel(const float* __restrict__ k_ws, const float* __restrict__ v_ws,
                        float* __restrict__ st)
{
    __shared__ float Ks[64][64];
    __shared__ float Vs[64][64];
    const int c = blockIdx.x, h = blockIdx.y;
    const int t = threadIdx.x;
    const float* Kg = k_ws + ((size_t)h * S_LEN + c * CHUNK) * DH;
    const float* Vg = v_ws + ((size_t)h * S_LEN + c * CHUNK) * DH;
#pragma unroll
    for (int u = 0; u < 4; ++u) {
        int f = u * 256 + t;
        ((float4*)&Ks[0][0])[f] = ((const float4*)Kg)[f];
        ((float4*)&Vs[0][0])[f] = ((const float4*)Vg)[f];
    }
    __syncthreads();

    const int tx = t & 15, ty = t >> 4;
    float acc[4][4];
#pragma unroll
    for (int i = 0; i < 4; ++i)
#pragma unroll
        for (int j = 0; j < 4; ++j) acc[i][j] = 0.0f;

    for (int s = 0; s < 64; ++s) {
        const float4 kd = *(const float4*)&Ks[s][ty * 4];
        const float4 ve = *(const float4*)&Vs[s][tx * 4];
        const float kv[4] = {kd.x, kd.y, kd.z, kd.w};
        const float vv[4] = {ve.x, ve.y, ve.z, ve.w};
#pragma unroll
        for (int i = 0; i < 4; ++i)
#pragma unroll
            for (int j = 0; j < 4; ++j) acc[i][j] += kv[i] * vv[j];
    }
    float* base = st + (size_t)(h * NCH + c) * ST_STRIDE;
#pragma unroll
    for (int i = 0; i < 4; ++i) {
        float4 o; o.x = acc[i][0]; o.y = acc[i][1]; o.z = acc[i][2]; o.w = acc[i][3];
        *(float4*)(base + (ty * 4 + i) * 64 + tx * 4) = o;
    }
    if (t < 64) {
        float s = 0.0f;
        for (int j = 0; j < 64; ++j) s += Ks[j][t];
        base[DH * DH + t] = s;
    }
}

// ---------------- Pass C: in-place exclusive prefix scan over chunks ----------------
__global__ __launch_bounds__(64)
void scan_kernel(float* __restrict__ st)
{
    const int h = blockIdx.y;
    const int e = blockIdx.x * 64 + threadIdx.x;
    float* p = st + (size_t)h * NCH * ST_STRIDE + e;
    float acc = 0.0f;
    for (int c = 0; c < NCH; ++c) {
        const float v = p[(size_t)c * ST_STRIDE];
        p[(size_t)c * ST_STRIDE] = acc;
        acc += v;
    }
}

// ---------------- Pass D: per (head, chunk) output ----------------
__global__ __launch_bounds__(256)
void attn_out_kernel(const float* __restrict__ q_ws, const float* __restrict__ k_ws,
                     const float* __restrict__ v_ws, const float* __restrict__ pfx,
                     ushort* __restrict__ out_pre)
{
    __shared__ float QsT[64][68];   // [d][i]
    __shared__ float KsT[64][68];   // [d][j]
    __shared__ float Vs[64][64];    // [j][e]
    __shared__ float As[64][65];    // [i][j]

    const int c = blockIdx.x, h = blockIdx.y;
    const int t = threadIdx.x, tx = t & 15, ty = t >> 4;
    const size_t cbase = ((size_t)h * S_LEN + c * CHUNK) * DH;
    const float* __restrict__ pb = pfx + (size_t)(h * NCH + c) * ST_STRIDE;

#pragma unroll
    for (int u = 0; u < 4; ++u) {
        int f = u * 256 + t;
        int cg = f >> 6, row = f & 63;
        const int col4 = cg * 4;
        const float4 qv = *(const float4*)(q_ws + cbase + (size_t)row * DH + col4);
        QsT[col4 + 0][row] = qv.x;
        QsT[col4 + 1][row] = qv.y;
        QsT[col4 + 2][row] = qv.z;
        QsT[col4 + 3][row] = qv.w;
        const float4 kv = *(const float4*)(k_ws + cbase + (size_t)row * DH + col4);
        KsT[col4 + 0][row] = kv.x;
        KsT[col4 + 1][row] = kv.y;
        KsT[col4 + 2][row] = kv.z;
        KsT[col4 + 3][row] = kv.w;
    }
#pragma unroll
    for (int u = 0; u < 4; ++u) {
        int f = u * 256 + t;
        ((float4*)&Vs[0][0])[f] = ((const float4*)(v_ws + cbase))[f];
    }
    __syncthreads();

    float a[4][4];
#pragma unroll
    for (int i = 0; i < 4; ++i)
#pragma unroll
        for (int j = 0; j < 4; ++j) a[i][j] = 0.0f;
    for (int d = 0; d < 64; ++d) {
        const float4 qd = *(const float4*)&QsT[d][ty * 4];
        const float4 kd = *(const float4*)&KsT[d][tx * 4];
        const float qv[4] = {qd.x, qd.y, qd.z, qd.w};
        const float kv[4] = {kd.x, kd.y, kd.z, kd.w};
#pragma unroll
        for (int i = 0; i < 4; ++i)
#pragma unroll
            for (int j = 0; j < 4; ++j) a[i][j] += qv[i] * kv[j];
    }
#pragma unroll
    for (int i = 0; i < 4; ++i)
#pragma unroll
        for (int j = 0; j < 4; ++j) {
            const int gi = ty * 4 + i, gj = tx * 4 + j;
            As[gi][gj] = (gj <= gi) ? a[i][j] : 0.0f;
        }

    float num[4][4];
#pragma unroll
    for (int i = 0; i < 4; ++i)
#pragma unroll
        for (int j = 0; j < 4; ++j) num[i][j] = 0.0f;
    float den[4] = {0.0f, 0.0f, 0.0f, 0.0f};
#pragma unroll 4
    for (int d = 0; d < 64; ++d) {
        const float4 qd = *(const float4*)&QsT[d][ty * 4];
        const float4 pe = *(const float4*)(pb + d * 64 + tx * 4);
        const float kp = pb[DH * DH + d];
        const float qv[4] = {qd.x, qd.y, qd.z, qd.w};
        const float pv[4] = {pe.x, pe.y, pe.z, pe.w};
#pragma unroll
        for (int i = 0; i < 4; ++i) {
#pragma unroll
            for (int j = 0; j < 4; ++j) num[i][j] += qv[i] * pv[j];
            den[i] += qv[i] * kp;
        }
    }
    __syncthreads();

    float rs[4] = {0.0f, 0.0f, 0.0f, 0.0f};
    for (int j = 0; j < 64; ++j) {
        const float4 ve = *(const float4*)&Vs[j][tx * 4];
        const float vv[4] = {ve.x, ve.y, ve.z, ve.w};
#pragma unroll
        for (int i = 0; i < 4; ++i) {
            const float aij = As[ty * 4 + i][j];
            rs[i] += aij;
            num[i][0] += aij * vv[0];
            num[i][1] += aij * vv[1];
            num[i][2] += aij * vv[2];
            num[i][3] += aij * vv[3];
        }
    }

#pragma unroll
    for (int i = 0; i < 4; ++i) {
        const float dn = den[i] + rs[i];
        const float r  = 1.0f / dn;
        const int srow = c * CHUNK + ty * 4 + i;
        ushort4 o;
        o.x = bf16r(num[i][0] * r); o.y = bf16r(num[i][1] * r);
        o.z = bf16r(num[i][2] * r); o.w = bf16r(num[i][3] * r);
        *(ushort4*)(out_pre + (size_t)srow * DM + h * DH + tx * 4) = o;
    }
}

extern "C" void kernel_launch(void* const* d_in, const int* in_sizes, int n_in,
                              void* d_out, int out_size, void* d_ws, size_t ws_size,
                              hipStream_t stream)
{
    const float* x    = (const float*)d_in[0];
    const float* Wq   = (const float*)d_in[1];
    const float* bq   = (const float*)d_in[2];
    const float* Wk   = (const float*)d_in[3];
    const float* bk   = (const float*)d_in[4];
    const float* Wv   = (const float*)d_in[5];
    const float* bv   = (const float*)d_in[6];
    const float* Wo   = (const float*)d_in[7];
    const float* bo   = (const float*)d_in[8];
    const float* beta = (const float*)d_in[9];
    float* out = (float*)d_out;

    float*  q_ws  = (float*)d_ws;                          // 3 x 2M floats (q|k|v)
    float*  k_ws  = q_ws + (size_t)NH * S_LEN * DH;
    float*  v_ws  = k_ws + (size_t)NH * S_LEN * DH;
    float*  st    = v_ws + (size_t)NH * S_LEN * DH;        // 16*32*4160 floats
    ushort* x_bf  = (ushort*)(st + (size_t)NH * NCH * ST_STRIDE);   // 2M bf16
    ushort* w_bf  = x_bf + (size_t)S_LEN * DM;                      // 4 x 1M bf16 (Wq|Wk|Wv|Wo)
    ushort* op_bf = w_bf + (size_t)4 * DM * DM;                     // 2M bf16

    const ushort* wo_bf = w_bf + (size_t)3 * DM * DM;

    cast_x_kernel<<<(S_LEN * DM) / 1024, 256, 0, stream>>>(x, x_bf);
    cast_w_kernel<<<dim3((DM * DM) / 1024, 4), 256, 0, stream>>>(Wq, Wk, Wv, Wo, w_bf);

    qkv_gemm_kernel<<<192, 512, 0, stream>>>(x_bf, w_bf, bq, bk, bv, beta, q_ws);

    chunk_state_kernel<<<dim3(NCH, NH), 256, 0, stream>>>(k_ws, v_ws, st);
    scan_kernel<<<dim3(ST_STRIDE / 64, NH), 64, 0, stream>>>(st);
    attn_out_kernel<<<dim3(NCH, NH), 256, 0, stream>>>(q_ws, k_ws, v_ws, st, op_bf);

    o_gemm_kernel<<<256, 256, 0, stream>>>(op_bf, wo_bf, bo, out);
}

// Round 8
// 105.177 us; speedup vs baseline: 1.0472x; 1.0472x over previous
//
#include <hip/hip_runtime.h>
#include <hip/hip_bf16.h>
#include <math.h>

#define S_LEN 2048
#define DM    1024
#define NH    16
#define DH    64
#define CHUNK 64
#define NCH   (S_LEN / CHUNK)          // 32
#define ST_STRIDE (DH * DH + DH)       // 4160 floats per (head,chunk) state

typedef __attribute__((ext_vector_type(8))) short bf16x8;   // 8 bf16 in 4 VGPRs
typedef __attribute__((ext_vector_type(4))) float f32x4;

__device__ __forceinline__ float softplus_f(float x) {
    return (x > 20.0f) ? x : log1pf(expf(x));
}

__device__ __forceinline__ ushort bf16r(float f) {   // round-to-nearest-even f32 -> bf16
    union { float f; unsigned int u; } c; c.f = f;
    unsigned int u = c.u;
    u = (u + 0x7FFFu + ((u >> 16) & 1u)) >> 16;
    return (ushort)u;
}

// ---------------- casts ----------------
__global__ __launch_bounds__(256) void cast_x_kernel(const float* __restrict__ src,
                                                     ushort* __restrict__ dst) {
    const int i = (blockIdx.x * 256 + threadIdx.x) * 4;
    const float4 v = *(const float4*)(src + i);
    ushort4 o; o.x = bf16r(v.x); o.y = bf16r(v.y); o.z = bf16r(v.z); o.w = bf16r(v.w);
    *(ushort4*)(dst + i) = o;
}

__global__ __launch_bounds__(256) void cast_w_kernel(const float* __restrict__ Wq,
                                                     const float* __restrict__ Wk,
                                                     const float* __restrict__ Wv,
                                                     const float* __restrict__ Wo,
                                                     ushort* __restrict__ dst) {
    const int y = blockIdx.y;
    const float* s = (y == 0) ? Wq : (y == 1) ? Wk : (y == 2) ? Wv : Wo;
    const int i = (blockIdx.x * 256 + threadIdx.x) * 4;
    const float4 v = *(const float4*)(s + i);
    ushort4 o; o.x = bf16r(v.x); o.y = bf16r(v.y); o.z = bf16r(v.z); o.w = bf16r(v.w);
    *(ushort4*)(dst + (size_t)y * (DM * DM) + i) = o;
}

// ------- bf16 MFMA GEMM core: simple 2-barrier loop (R3-proven), granule swizzle -------
// C = A @ B^T.  A: [M][1024] bf16 rm, B: [N][1024] bf16 rm (row = output feature).
// BM x BN tile, BK=32, WRxWC waves (64*WR*WC threads), wave sub-tile (BM/WR) x (BN/WC).
// Small tiles on purpose: grid must exceed 2x256 blocks so 2-3 blocks/CU co-reside --
// inter-block overlap (m114) hides the staging/barrier stalls that R4-R7's in-block
// pipelining could not (all schedule variants = ~50us at 1 block/CU; m102: co-residency
// is worth 2.6x at fixed structure).
// Swizzle (verified 0-conflict R4-R7): 16-row 1KB chunks; row r's four 16B granules
// permuted g_phys = g_log ^ ((r>>1)&3); linear gload_lds dest + inverse-swizzled global
// source col (rule 21); fragment reads apply the same XOR.
template<int BM, int BN, int WR, int WC>
__device__ __forceinline__ void gemm_core(const ushort* __restrict__ A,
                                          const ushort* __restrict__ Bw,
                                          int m0, int n0,
                                          ushort* Als, ushort* Bls,
                                          f32x4 acc[BM / (WR * 16)][BN / (WC * 16)])
{
    constexpr int MF = BM / (WR * 16);
    constexpr int NF = BN / (WC * 16);
    constexpr int NW = WR * WC;
    constexpr int AC = BM / 16;            // A chunks per K-step
    constexpr int TC = (BM + BN) / 16;     // total chunks per K-step

    const int t = threadIdx.x;
    const int w = t >> 6, l = t & 63;
    const int wr = w / WC, wc = w % WC;

#pragma unroll
    for (int mi = 0; mi < MF; ++mi)
#pragma unroll
        for (int ni = 0; ni < NF; ++ni) acc[mi][ni] = (f32x4){0.f, 0.f, 0.f, 0.f};

    const int srow = l >> 2;                               // row within 16-row chunk
    const int scol = ((l & 3) ^ ((l >> 3) & 3)) * 8;       // inverse-swizzled source col
    const int frow = l & 15;                               // fragment row
    const int gofs = ((l >> 4) ^ ((l >> 1) & 3)) * 8;      // swizzled fragment col

    for (int kt = 0; kt < DM; kt += 32) {
#pragma unroll
        for (int k2 = 0; k2 < TC / NW; ++k2) {
            const int ci = w + k2 * NW;                    // wave-uniform chunk id
            if (ci < AC) {
                __builtin_amdgcn_global_load_lds(
                    (const __attribute__((address_space(1))) void*)(A + (size_t)(m0 + ci * 16 + srow) * DM + kt + scol),
                    (__attribute__((address_space(3))) void*)(Als + ci * 512), 16, 0, 0);
            } else {
                __builtin_amdgcn_global_load_lds(
                    (const __attribute__((address_space(1))) void*)(Bw + (size_t)(n0 + (ci - AC) * 16 + srow) * DM + kt + scol),
                    (__attribute__((address_space(3))) void*)(Bls + (ci - AC) * 512), 16, 0, 0);
            }
        }
        __syncthreads();   // drains vmcnt -> staged data visible

        bf16x8 af[MF], bfr[NF];
#pragma unroll
        for (int mi = 0; mi < MF; ++mi)
            af[mi] = *(const bf16x8*)&Als[(wr * (BM / WR) + mi * 16 + frow) * 32 + gofs];
#pragma unroll
        for (int ni = 0; ni < NF; ++ni)
            bfr[ni] = *(const bf16x8*)&Bls[(wc * (BN / WC) + ni * 16 + frow) * 32 + gofs];
#pragma unroll
        for (int mi = 0; mi < MF; ++mi)
#pragma unroll
            for (int ni = 0; ni < NF; ++ni)
                acc[mi][ni] = __builtin_amdgcn_mfma_f32_16x16x32_bf16(af[mi], bfr[ni], acc[mi][ni], 0, 0, 0);

        __syncthreads();   // protect LDS before next stage
    }
}

// Fused QKV GEMM: A=Xb [2048][1024], B=Wqkv [3072][1024] (Wq|Wk|Wv).
// BM=64 x BN=128 tiles -> 32x24 = 768 blocks (3 blocks/CU), 4 waves (2x2), LDS 12KB.
// XCD-bijective swizzle (768%8==0), m-fastest: each XCD re-reads X from its own L2.
__global__ __launch_bounds__(256)
void qkv_gemm_kernel(const ushort* __restrict__ Xb, const ushort* __restrict__ Wqkv,
                     const float* __restrict__ bq, const float* __restrict__ bk,
                     const float* __restrict__ bv,
                     const float* __restrict__ beta,
                     float* __restrict__ qkv /* q|k|v contiguous */)
{
    __shared__ ushort Als[64 * 32];
    __shared__ ushort Bls[128 * 32];
    const int b = blockIdx.x;
    const int logical = (b & 7) * 96 + (b >> 3);      // XCD x owns 96 consecutive logicals
    const int mb = logical & 31, nb = logical >> 5;   // m-fastest within XCD
    const int m0 = mb * 64, n0 = nb * 128;
    const int z  = nb >> 3;                           // 0:q 1:k 2:v
    const int nz0 = (nb & 7) * 128;                   // col base within this z
    const float* bias = (z == 0) ? bq : (z == 1) ? bk : bv;

    f32x4 acc[2][4];
    gemm_core<64, 128, 2, 2>(Xb, Wqkv, m0, n0, Als, Bls, acc);

    const int t = threadIdx.x, w = t >> 6, l = t & 63;
    const int wr = w >> 1, wc = w & 1;
    float* outz = qkv + (size_t)z * (NH * S_LEN * DH);

#pragma unroll
    for (int ni = 0; ni < 4; ++ni) {
        const int col = nz0 + wc * 64 + ni * 16 + (l & 15);
        const int h = col >> 6, d = col & 63;
        const float bcol = bias[col];
        const float inv = (z < 2) ? (1.0f / (8.0f * expf(beta[h]))) : 1.0f;
#pragma unroll
        for (int mi = 0; mi < 2; ++mi) {
            const int rbase = m0 + wr * 32 + mi * 16 + (l >> 4) * 4;
#pragma unroll
            for (int r = 0; r < 4; ++r) {
                float v = acc[mi][ni][r] + bcol;
                if (z < 2) v = softplus_f(v * inv);
                outz[((size_t)h * S_LEN + rbase + r) * DH + d] = v;
            }
        }
    }
}

// O projection: C = out_pre(bf16) @ Wo^T + bo -> fp32 [2048][1024].
// BM=64 x BN=64 -> 32x16 = 512 blocks (2 blocks/CU), 4 waves (2x2), LDS 8KB.
__global__ __launch_bounds__(256)
void o_gemm_kernel(const ushort* __restrict__ Ab, const ushort* __restrict__ Wob,
                   const float* __restrict__ bo, float* __restrict__ out)
{
    __shared__ ushort Als[64 * 32];
    __shared__ ushort Bls[64 * 32];
    const int b = blockIdx.x;
    const int logical = (b & 7) * 64 + (b >> 3);
    const int mb = logical & 31, nb = logical >> 5;   // nb in [0,16)
    const int m0 = mb * 64, n0 = nb * 64;

    f32x4 acc[2][2];
    gemm_core<64, 64, 2, 2>(Ab, Wob, m0, n0, Als, Bls, acc);

    const int t = threadIdx.x, w = t >> 6, l = t & 63;
    const int wr = w >> 1, wc = w & 1;
#pragma unroll
    for (int ni = 0; ni < 2; ++ni) {
        const int col = n0 + wc * 32 + ni * 16 + (l & 15);
        const float bcol = bo[col];
#pragma unroll
        for (int mi = 0; mi < 2; ++mi) {
            const int rbase = m0 + wr * 32 + mi * 16 + (l >> 4) * 4;
#pragma unroll
            for (int r = 0; r < 4; ++r)
                out[(size_t)(rbase + r) * DM + col] = acc[mi][ni][r] + bcol;
        }
    }
}

// ---------------- Pass B: per (head, chunk) state ----------------
__global__ __launch_bounds__(256)
void chunk_state_kernel(const float* __restrict__ k_ws, const float* __restrict__ v_ws,
                        float* __restrict__ st)
{
    __shared__ float Ks[64][64];
    __shared__ float Vs[64][64];
    const int c = blockIdx.x, h = blockIdx.y;
    const int t = threadIdx.x;
    const float* Kg = k_ws + ((size_t)h * S_LEN + c * CHUNK) * DH;
    const float* Vg = v_ws + ((size_t)h * S_LEN + c * CHUNK) * DH;
#pragma unroll
    for (int u = 0; u < 4; ++u) {
        int f = u * 256 + t;
        ((float4*)&Ks[0][0])[f] = ((const float4*)Kg)[f];
        ((float4*)&Vs[0][0])[f] = ((const float4*)Vg)[f];
    }
    __syncthreads();

    const int tx = t & 15, ty = t >> 4;
    float acc[4][4];
#pragma unroll
    for (int i = 0; i < 4; ++i)
#pragma unroll
        for (int j = 0; j < 4; ++j) acc[i][j] = 0.0f;

    for (int s = 0; s < 64; ++s) {
        const float4 kd = *(const float4*)&Ks[s][ty * 4];
        const float4 ve = *(const float4*)&Vs[s][tx * 4];
        const float kv[4] = {kd.x, kd.y, kd.z, kd.w};
        const float vv[4] = {ve.x, ve.y, ve.z, ve.w};
#pragma unroll
        for (int i = 0; i < 4; ++i)
#pragma unroll
            for (int j = 0; j < 4; ++j) acc[i][j] += kv[i] * vv[j];
    }
    float* base = st + (size_t)(h * NCH + c) * ST_STRIDE;
#pragma unroll
    for (int i = 0; i < 4; ++i) {
        float4 o; o.x = acc[i][0]; o.y = acc[i][1]; o.z = acc[i][2]; o.w = acc[i][3];
        *(float4*)(base + (ty * 4 + i) * 64 + tx * 4) = o;
    }
    if (t < 64) {
        float s = 0.0f;
        for (int j = 0; j < 64; ++j) s += Ks[j][t];
        base[DH * DH + t] = s;
    }
}

// ---------------- Pass C: in-place exclusive prefix scan over chunks ----------------
__global__ __launch_bounds__(64)
void scan_kernel(float* __restrict__ st)
{
    const int h = blockIdx.y;
    const int e = blockIdx.x * 64 + threadIdx.x;
    float* p = st + (size_t)h * NCH * ST_STRIDE + e;
    float acc = 0.0f;
    for (int c = 0; c < NCH; ++c) {
        const float v = p[(size_t)c * ST_STRIDE];
        p[(size_t)c * ST_STRIDE] = acc;
        acc += v;
    }
}

// ---------------- Pass D: per (head, chunk) output ----------------
__global__ __launch_bounds__(256)
void attn_out_kernel(const float* __restrict__ q_ws, const float* __restrict__ k_ws,
                     const float* __restrict__ v_ws, const float* __restrict__ pfx,
                     ushort* __restrict__ out_pre)
{
    __shared__ float QsT[64][68];   // [d][i]
    __shared__ float KsT[64][68];   // [d][j]
    __shared__ float Vs[64][64];    // [j][e]
    __shared__ float As[64][65];    // [i][j]

    const int c = blockIdx.x, h = blockIdx.y;
    const int t = threadIdx.x, tx = t & 15, ty = t >> 4;
    const size_t cbase = ((size_t)h * S_LEN + c * CHUNK) * DH;
    const float* __restrict__ pb = pfx + (size_t)(h * NCH + c) * ST_STRIDE;

#pragma unroll
    for (int u = 0; u < 4; ++u) {
        int f = u * 256 + t;
        int cg = f >> 6, row = f & 63;
        const int col4 = cg * 4;
        const float4 qv = *(const float4*)(q_ws + cbase + (size_t)row * DH + col4);
        QsT[col4 + 0][row] = qv.x;
        QsT[col4 + 1][row] = qv.y;
        QsT[col4 + 2][row] = qv.z;
        QsT[col4 + 3][row] = qv.w;
        const float4 kv = *(const float4*)(k_ws + cbase + (size_t)row * DH + col4);
        KsT[col4 + 0][row] = kv.x;
        KsT[col4 + 1][row] = kv.y;
        KsT[col4 + 2][row] = kv.z;
        KsT[col4 + 3][row] = kv.w;
    }
#pragma unroll
    for (int u = 0; u < 4; ++u) {
        int f = u * 256 + t;
        ((float4*)&Vs[0][0])[f] = ((const float4*)(v_ws + cbase))[f];
    }
    __syncthreads();

    float a[4][4];
#pragma unroll
    for (int i = 0; i < 4; ++i)
#pragma unroll
        for (int j = 0; j < 4; ++j) a[i][j] = 0.0f;
    for (int d = 0; d < 64; ++d) {
        const float4 qd = *(const float4*)&QsT[d][ty * 4];
        const float4 kd = *(const float4*)&KsT[d][tx * 4];
        const float qv[4] = {qd.x, qd.y, qd.z, qd.w};
        const float kv[4] = {kd.x, kd.y, kd.z, kd.w};
#pragma unroll
        for (int i = 0; i < 4; ++i)
#pragma unroll
            for (int j = 0; j < 4; ++j) a[i][j] += qv[i] * kv[j];
    }
#pragma unroll
    for (int i = 0; i < 4; ++i)
#pragma unroll
        for (int j = 0; j < 4; ++j) {
            const int gi = ty * 4 + i, gj = tx * 4 + j;
            As[gi][gj] = (gj <= gi) ? a[i][j] : 0.0f;
        }

    float num[4][4];
#pragma unroll
    for (int i = 0; i < 4; ++i)
#pragma unroll
        for (int j = 0; j < 4; ++j) num[i][j] = 0.0f;
    float den[4] = {0.0f, 0.0f, 0.0f, 0.0f};
#pragma unroll 4
    for (int d = 0; d < 64; ++d) {
        const float4 qd = *(const float4*)&QsT[d][ty * 4];
        const float4 pe = *(const float4*)(pb + d * 64 + tx * 4);
        const float kp = pb[DH * DH + d];
        const float qv[4] = {qd.x, qd.y, qd.z, qd.w};
        const float pv[4] = {pe.x, pe.y, pe.z, pe.w};
#pragma unroll
        for (int i = 0; i < 4; ++i) {
#pragma unroll
            for (int j = 0; j < 4; ++j) num[i][j] += qv[i] * pv[j];
            den[i] += qv[i] * kp;
        }
    }
    __syncthreads();

    float rs[4] = {0.0f, 0.0f, 0.0f, 0.0f};
    for (int j = 0; j < 64; ++j) {
        const float4 ve = *(const float4*)&Vs[j][tx * 4];
        const float vv[4] = {ve.x, ve.y, ve.z, ve.w};
#pragma unroll
        for (int i = 0; i < 4; ++i) {
            const float aij = As[ty * 4 + i][j];
            rs[i] += aij;
            num[i][0] += aij * vv[0];
            num[i][1] += aij * vv[1];
            num[i][2] += aij * vv[2];
            num[i][3] += aij * vv[3];
        }
    }

#pragma unroll
    for (int i = 0; i < 4; ++i) {
        const float dn = den[i] + rs[i];
        const float r  = 1.0f / dn;
        const int srow = c * CHUNK + ty * 4 + i;
        ushort4 o;
        o.x = bf16r(num[i][0] * r); o.y = bf16r(num[i][1] * r);
        o.z = bf16r(num[i][2] * r); o.w = bf16r(num[i][3] * r);
        *(ushort4*)(out_pre + (size_t)srow * DM + h * DH + tx * 4) = o;
    }
}

extern "C" void kernel_launch(void* const* d_in, const int* in_sizes, int n_in,
                              void* d_out, int out_size, void* d_ws, size_t ws_size,
                              hipStream_t stream)
{
    const float* x    = (const float*)d_in[0];
    const float* Wq   = (const float*)d_in[1];
    const float* bq   = (const float*)d_in[2];
    const float* Wk   = (const float*)d_in[3];
    const float* bk   = (const float*)d_in[4];
    const float* Wv   = (const float*)d_in[5];
    const float* bv   = (const float*)d_in[6];
    const float* Wo   = (const float*)d_in[7];
    const float* bo   = (const float*)d_in[8];
    const float* beta = (const float*)d_in[9];
    float* out = (float*)d_out;

    float*  q_ws  = (float*)d_ws;                          // 3 x 2M floats (q|k|v)
    float*  k_ws  = q_ws + (size_t)NH * S_LEN * DH;
    float*  v_ws  = k_ws + (size_t)NH * S_LEN * DH;
    float*  st    = v_ws + (size_t)NH * S_LEN * DH;        // 16*32*4160 floats
    ushort* x_bf  = (ushort*)(st + (size_t)NH * NCH * ST_STRIDE);   // 2M bf16
    ushort* w_bf  = x_bf + (size_t)S_LEN * DM;                      // 4 x 1M bf16 (Wq|Wk|Wv|Wo)
    ushort* op_bf = w_bf + (size_t)4 * DM * DM;                     // 2M bf16

    const ushort* wo_bf = w_bf + (size_t)3 * DM * DM;

    cast_x_kernel<<<(S_LEN * DM) / 1024, 256, 0, stream>>>(x, x_bf);
    cast_w_kernel<<<dim3((DM * DM) / 1024, 4), 256, 0, stream>>>(Wq, Wk, Wv, Wo, w_bf);

    qkv_gemm_kernel<<<768, 256, 0, stream>>>(x_bf, w_bf, bq, bk, bv, beta, q_ws);

    chunk_state_kernel<<<dim3(NCH, NH), 256, 0, stream>>>(k_ws, v_ws, st);
    scan_kernel<<<dim3(ST_STRIDE / 64, NH), 64, 0, stream>>>(st);
    attn_out_kernel<<<dim3(NCH, NH), 256, 0, stream>>>(q_ws, k_ws, v_ws, st, op_bf);

    o_gemm_kernel<<<512, 256, 0, stream>>>(op_bf, wo_bf, bo, out);
}